// Round 1
// baseline (257.790 us; speedup 1.0000x reference)
//
#include <hip/hip_runtime.h>

#define SEQ    2048
#define NBATCH 2
#define NHEAD  16
#define HD     64
#define MD     1024
#define TOK    (SEQ * NBATCH)   // 4096

typedef __attribute__((ext_vector_type(4))) float f32x4;
typedef __attribute__((ext_vector_type(8))) short bf16x8;
typedef __attribute__((ext_vector_type(8))) unsigned short u16x8;

__device__ __forceinline__ unsigned short f2bf(float f) {
  union { float f; unsigned int u; } x; x.f = f;
  unsigned int u = x.u + 0x7fffu + ((x.u >> 16) & 1u);   // RNE; inputs are finite
  return (unsigned short)(u >> 16);
}

__device__ __forceinline__ void gload_lds16(const void* g, void* l) {
  typedef const __attribute__((address_space(1))) unsigned int* gp_t;
  typedef __attribute__((address_space(3))) unsigned int* lp_t;
  __builtin_amdgcn_global_load_lds((gp_t)g, (lp_t)l, 16, 0, 0);
}

// ---------------- fp32 -> bf16 convert, 8 elems/thread ----------------
__global__ __launch_bounds__(256) void cvt_bf16(const float* __restrict__ in,
                                                unsigned short* __restrict__ out,
                                                int n8) {
  int i = blockIdx.x * 256 + threadIdx.x;
  if (i >= n8) return;
  const float4* p = (const float4*)in + (size_t)i * 2;
  float4 a = p[0];
  float4 b = p[1];
  u16x8 o;
  o[0] = f2bf(a.x); o[1] = f2bf(a.y); o[2] = f2bf(a.z); o[3] = f2bf(a.w);
  o[4] = f2bf(b.x); o[5] = f2bf(b.y); o[6] = f2bf(b.z); o[7] = f2bf(b.w);
  *((u16x8*)out + i) = o;
}

// ------------- GEMM: C[M,N] = A[M,K] @ B[N,K]^T + bias ----------------
// m97 structure: 128x128 tile, BK=32, 4 waves (2x2), global_load_lds w16.
// MODE 0: bf16 out scattered to [B,H,S,D]; val = (acc + bias[col]) * scale
// MODE 1: bf16 out scattered to [B,H,D,S]; rows are channels (A = weight)
// MODE 2: fp32 out row-major [M, MD];      val = acc + bias[col]
template <int MODE>
__global__ __launch_bounds__(256) void gemm_bt(const unsigned short* __restrict__ A,
                                               const unsigned short* __restrict__ B,
                                               const float* __restrict__ bias,
                                               void* __restrict__ Cout,
                                               int K, float scale) {
  __shared__ unsigned short sA[128 * 32];
  __shared__ unsigned short sB[128 * 32];
  const int tid  = threadIdx.x;
  const int lane = tid & 63;
  const int wave = tid >> 6;
  const int wm   = (wave >> 1) << 6;
  const int wn   = (wave & 1) << 6;
  const int l15  = lane & 15;
  const int g    = lane >> 4;
  const int bM   = blockIdx.y << 7;
  const int bN   = blockIdx.x << 7;

  f32x4 acc[4][4];
#pragma unroll
  for (int a_ = 0; a_ < 4; ++a_)
#pragma unroll
    for (int b_ = 0; b_ < 4; ++b_)
      acc[a_][b_] = f32x4{0.f, 0.f, 0.f, 0.f};

  const int c0 = tid, c1 = tid + 256;
  const int r0 = c0 >> 2, cc0 = c0 & 3;
  const int r1 = c1 >> 2, cc1 = c1 & 3;

  const int nk = K >> 5;
  for (int kt = 0; kt < nk; ++kt) {
    const int k0 = kt << 5;
    gload_lds16(A + (size_t)(bM + r0) * K + k0 + cc0 * 8, (char*)sA + c0 * 16);
    gload_lds16(A + (size_t)(bM + r1) * K + k0 + cc1 * 8, (char*)sA + c1 * 16);
    gload_lds16(B + (size_t)(bN + r0) * K + k0 + cc0 * 8, (char*)sB + c0 * 16);
    gload_lds16(B + (size_t)(bN + r1) * K + k0 + cc1 * 8, (char*)sB + c1 * 16);
    __syncthreads();
    bf16x8 af[4], bfr[4];
#pragma unroll
    for (int f = 0; f < 4; ++f) {
      af[f]  = *(const bf16x8*)&sA[(wm + f * 16 + l15) * 32 + g * 8];
      bfr[f] = *(const bf16x8*)&sB[(wn + f * 16 + l15) * 32 + g * 8];
    }
#pragma unroll
    for (int mf = 0; mf < 4; ++mf)
#pragma unroll
      for (int nf = 0; nf < 4; ++nf)
        acc[mf][nf] = __builtin_amdgcn_mfma_f32_16x16x32_bf16(af[mf], bfr[nf], acc[mf][nf], 0, 0, 0);
    __syncthreads();
  }

  if constexpr (MODE == 0) {
    unsigned short* O = (unsigned short*)Cout;
#pragma unroll
    for (int nf = 0; nf < 4; ++nf) {
      const int cch = bN + wn + nf * 16 + l15;
      const float bb = bias[cch];
      const int h = cch >> 6, d = cch & 63;
#pragma unroll
      for (int mf = 0; mf < 4; ++mf)
#pragma unroll
        for (int i = 0; i < 4; ++i) {
          const int t = bM + wm + mf * 16 + (g << 2) + i;
          const int b = t & 1, s = t >> 1;
          O[((((b << 4) + h) * SEQ + s) << 6) + d] = f2bf((acc[mf][nf][i] + bb) * scale);
        }
    }
  } else if constexpr (MODE == 1) {
    unsigned short* O = (unsigned short*)Cout;
#pragma unroll
    for (int mf = 0; mf < 4; ++mf)
#pragma unroll
      for (int i = 0; i < 4; ++i) {
        const int rch = bM + wm + mf * 16 + (g << 2) + i;
        const float bb = bias[rch];
        const int h = rch >> 6, d = rch & 63;
#pragma unroll
        for (int nf = 0; nf < 4; ++nf) {
          const int t = bN + wn + nf * 16 + l15;
          const int b = t & 1, s = t >> 1;
          O[((((b << 4) + h) << 6) + d) * SEQ + s] = f2bf(acc[mf][nf][i] + bb);
        }
      }
  } else {
    float* O = (float*)Cout;
#pragma unroll
    for (int nf = 0; nf < 4; ++nf) {
      const int cch = bN + wn + nf * 16 + l15;
      const float bb = bias[cch];
#pragma unroll
      for (int mf = 0; mf < 4; ++mf)
#pragma unroll
        for (int i = 0; i < 4; ++i) {
          const int t = bM + wm + mf * 16 + (g << 2) + i;
          O[(size_t)t * MD + cch] = acc[mf][nf][i] + bb;
        }
    }
  }
}

// --------------------- flash attention forward -------------------------
// grid: (SEQ/128, NBATCH*NHEAD); 4 waves x 32 q-rows; KV tile = 64.
// Q: [B,H,S,D] bf16 (pre-scaled by 1/8), K: [B,H,S,D], V: [B,H,D,S] bf16.
// Out: token-major [TOK, MD] bf16.
__global__ __launch_bounds__(256) void attn_fwd(const unsigned short* __restrict__ Qg,
                                                const unsigned short* __restrict__ Kg,
                                                const unsigned short* __restrict__ Vg,
                                                unsigned short* __restrict__ Xout) {
  __shared__ unsigned short sK[64 * 64];   // [k][d], XOR-swizzled
  __shared__ unsigned short sV[64 * 64];   // [d][k], XOR-swizzled
  __shared__ unsigned short sP[128 * 64];  // [q][k], XOR-swizzled

  const int tid  = threadIdx.x;
  const int lane = tid & 63;
  const int wave = tid >> 6;
  const int l15  = lane & 15;
  const int g    = lane >> 4;
  const int bh   = blockIdx.y;
  const int q0   = blockIdx.x << 7;
  const int wq   = wave << 5;

  const unsigned short* Qb = Qg + (size_t)bh * (SEQ * HD);
  const unsigned short* Kb = Kg + (size_t)bh * (SEQ * HD);
  const unsigned short* Vb = Vg + (size_t)bh * (HD * SEQ);

  // Q fragments (held in registers for the whole block)
  bf16x8 qf[2][2];
#pragma unroll
  for (int mf = 0; mf < 2; ++mf)
#pragma unroll
    for (int ks = 0; ks < 2; ++ks)
      qf[mf][ks] = *(const bf16x8*)&Qb[(size_t)(q0 + wq + mf * 16 + l15) * HD + ks * 32 + g * 8];

  f32x4 acc_o[2][4];
  float mrow[2][4], lrow[2][4];
#pragma unroll
  for (int mf = 0; mf < 2; ++mf)
#pragma unroll
    for (int i = 0; i < 4; ++i) { mrow[mf][i] = -1e30f; lrow[mf][i] = 0.f; }
#pragma unroll
  for (int mf = 0; mf < 2; ++mf)
#pragma unroll
    for (int nf = 0; nf < 4; ++nf)
      acc_o[mf][nf] = f32x4{0.f, 0.f, 0.f, 0.f};

  for (int kt = 0; kt < SEQ / 64; ++kt) {
    const int k0 = kt << 6;
    // stage K tile [64 k][64 d] and V^T tile [64 d][64 k]: linear LDS dest,
    // inverse-swizzled global source (swizzle: byte ^= (row&7)<<4)
#pragma unroll
    for (int j = 0; j < 2; ++j) {
      const int c = tid + (j << 8);              // 0..511 16B chunks
      const int p = c << 4;                      // phys byte offset
      const int row = p >> 7;                    // row unaffected by swizzle
      const int lcol = (p ^ ((row & 7) << 4)) & 127;
      gload_lds16((const char*)Kb + (size_t)(k0 + row) * (HD * 2) + lcol, (char*)sK + p);
      gload_lds16((const char*)Vb + (size_t)row * (SEQ * 2) + (k0 << 1) + lcol, (char*)sV + p);
    }
    __syncthreads();

    // S = Q K^T (scale already folded into Q)
    f32x4 accs[2][4];
#pragma unroll
    for (int mf = 0; mf < 2; ++mf)
#pragma unroll
      for (int nf = 0; nf < 4; ++nf)
        accs[mf][nf] = f32x4{0.f, 0.f, 0.f, 0.f};
    bf16x8 kf[4][2];
#pragma unroll
    for (int nf = 0; nf < 4; ++nf) {
      const int row = nf * 16 + l15;
#pragma unroll
      for (int ks = 0; ks < 2; ++ks) {
        const int off = ((row << 7) + ((ks * 32 + g * 8) << 1)) ^ ((row & 7) << 4);
        kf[nf][ks] = *(const bf16x8*)((const char*)sK + off);
      }
    }
#pragma unroll
    for (int mf = 0; mf < 2; ++mf)
#pragma unroll
      for (int nf = 0; nf < 4; ++nf)
#pragma unroll
        for (int ks = 0; ks < 2; ++ks)
          accs[mf][nf] = __builtin_amdgcn_mfma_f32_16x16x32_bf16(qf[mf][ks], kf[nf][ks], accs[mf][nf], 0, 0, 0);

    // online softmax; row for (mf,i) at this lane = wq + mf*16 + 4*g + i
#pragma unroll
    for (int mf = 0; mf < 2; ++mf) {
#pragma unroll
      for (int i = 0; i < 4; ++i) {
        float mx = fmaxf(fmaxf(accs[mf][0][i], accs[mf][1][i]),
                         fmaxf(accs[mf][2][i], accs[mf][3][i]));
        mx = fmaxf(mx, __shfl_xor(mx, 1));
        mx = fmaxf(mx, __shfl_xor(mx, 2));
        mx = fmaxf(mx, __shfl_xor(mx, 4));
        mx = fmaxf(mx, __shfl_xor(mx, 8));
        const float mold = mrow[mf][i];
        const float mnew = fmaxf(mold, mx);
        const float resc = __expf(mold - mnew);
        mrow[mf][i] = mnew;
        float rsum = 0.f;
#pragma unroll
        for (int nf = 0; nf < 4; ++nf) {
          const float pv = __expf(accs[mf][nf][i] - mnew);
          accs[mf][nf][i] = pv;
          rsum += pv;
        }
        rsum += __shfl_xor(rsum, 1);
        rsum += __shfl_xor(rsum, 2);
        rsum += __shfl_xor(rsum, 4);
        rsum += __shfl_xor(rsum, 8);
        lrow[mf][i] = lrow[mf][i] * resc + rsum;
#pragma unroll
        for (int nf = 0; nf < 4; ++nf) acc_o[mf][nf][i] *= resc;
      }
    }

    // P (C-layout) -> LDS, bf16, swizzled. Same-wave producer/consumer.
#pragma unroll
    for (int mf = 0; mf < 2; ++mf)
#pragma unroll
      for (int nf = 0; nf < 4; ++nf)
#pragma unroll
        for (int i = 0; i < 4; ++i) {
          const int qr = wq + mf * 16 + (g << 2) + i;
          const int kc = nf * 16 + l15;
          const int off = ((qr << 7) + (kc << 1)) ^ ((qr & 7) << 4);
          *(unsigned short*)((char*)sP + off) = f2bf(accs[mf][nf][i]);
        }
    asm volatile("s_waitcnt lgkmcnt(0)" ::: "memory");

    // O += P V  (A = P rows, B = V^T rows)
    bf16x8 pf[2][2], vf[4][2];
#pragma unroll
    for (int mf = 0; mf < 2; ++mf)
#pragma unroll
      for (int ks = 0; ks < 2; ++ks) {
        const int qr = wq + mf * 16 + l15;
        const int off = ((qr << 7) + ((ks * 32 + g * 8) << 1)) ^ ((qr & 7) << 4);
        pf[mf][ks] = *(const bf16x8*)((const char*)sP + off);
      }
#pragma unroll
    for (int nf = 0; nf < 4; ++nf)
#pragma unroll
      for (int ks = 0; ks < 2; ++ks) {
        const int dr = nf * 16 + l15;
        const int off = ((dr << 7) + ((ks * 32 + g * 8) << 1)) ^ ((dr & 7) << 4);
        vf[nf][ks] = *(const bf16x8*)((const char*)sV + off);
      }
#pragma unroll
    for (int mf = 0; mf < 2; ++mf)
#pragma unroll
      for (int nf = 0; nf < 4; ++nf)
#pragma unroll
        for (int ks = 0; ks < 2; ++ks)
          acc_o[mf][nf] = __builtin_amdgcn_mfma_f32_16x16x32_bf16(pf[mf][ks], vf[nf][ks], acc_o[mf][nf], 0, 0, 0);

    __syncthreads();
  }

  // epilogue: x[t, h*64+d] = O / l
  const int b = bh >> 4, h = bh & 15;
#pragma unroll
  for (int mf = 0; mf < 2; ++mf) {
#pragma unroll
    for (int i = 0; i < 4; ++i) {
      const float inv = 1.f / lrow[mf][i];
      const int s = q0 + wq + mf * 16 + (g << 2) + i;
      const int t = s * NBATCH + b;
#pragma unroll
      for (int nf = 0; nf < 4; ++nf) {
        const int col = (h << 6) + nf * 16 + l15;
        Xout[(size_t)t * MD + col] = f2bf(acc_o[mf][nf][i] * inv);
      }
    }
  }
}

extern "C" void kernel_launch(void* const* d_in, const int* in_sizes, int n_in,
                              void* d_out, int out_size, void* d_ws, size_t ws_size,
                              hipStream_t stream) {
  const float* query = (const float*)d_in[0];
  const float* key   = (const float*)d_in[1];
  const float* value = (const float*)d_in[2];
  // d_in[3] = mask: dead code in reference
  const float* Wq = (const float*)d_in[4];
  const float* bq = (const float*)d_in[5];
  const float* Wk = (const float*)d_in[6];
  const float* bk = (const float*)d_in[7];
  const float* Wv = (const float*)d_in[8];
  const float* bv = (const float*)d_in[9];
  const float* Wo = (const float*)d_in[10];
  const float* bo = (const float*)d_in[11];

  char* ws = (char*)d_ws;
  const size_t MB = 1024 * 1024;
  unsigned short* Xq  = (unsigned short*)(ws + 0 * MB);   // [TOK,MD] bf16
  unsigned short* Xk  = (unsigned short*)(ws + 8 * MB);
  unsigned short* Xv  = (unsigned short*)(ws + 16 * MB);
  unsigned short* Wqb = (unsigned short*)(ws + 24 * MB);
  unsigned short* Wkb = (unsigned short*)(ws + 26 * MB);
  unsigned short* Wvb = (unsigned short*)(ws + 28 * MB);
  unsigned short* Wob = (unsigned short*)(ws + 30 * MB);
  unsigned short* Qb  = (unsigned short*)(ws + 32 * MB);  // [B,H,S,D]
  unsigned short* Kb  = (unsigned short*)(ws + 40 * MB);  // [B,H,S,D]
  unsigned short* Vb  = (unsigned short*)(ws + 48 * MB);  // [B,H,D,S]
  unsigned short* Xa  = Xq;  // alias: Xq dead after Q projection

  cvt_bf16<<<TOK * MD / 8 / 256, 256, 0, stream>>>(query, Xq, TOK * MD / 8);
  cvt_bf16<<<TOK * MD / 8 / 256, 256, 0, stream>>>(key, Xk, TOK * MD / 8);
  cvt_bf16<<<TOK * MD / 8 / 256, 256, 0, stream>>>(value, Xv, TOK * MD / 8);
  cvt_bf16<<<MD * MD / 8 / 256, 256, 0, stream>>>(Wq, Wqb, MD * MD / 8);
  cvt_bf16<<<MD * MD / 8 / 256, 256, 0, stream>>>(Wk, Wkb, MD * MD / 8);
  cvt_bf16<<<MD * MD / 8 / 256, 256, 0, stream>>>(Wv, Wvb, MD * MD / 8);
  cvt_bf16<<<MD * MD / 8 / 256, 256, 0, stream>>>(Wo, Wob, MD * MD / 8);

  dim3 gQK(MD / 128, TOK / 128);   // (8, 32)
  gemm_bt<0><<<gQK, 256, 0, stream>>>(Xq, Wqb, bq, Qb, MD, 0.125f);  // Q pre-scaled
  gemm_bt<0><<<gQK, 256, 0, stream>>>(Xk, Wkb, bk, Kb, MD, 1.0f);
  dim3 gV(TOK / 128, MD / 128);    // (32, 8): swapped operands -> V^T out
  gemm_bt<1><<<gV, 256, 0, stream>>>(Wvb, Xv, bv, Vb, MD, 1.0f);

  dim3 gA(SEQ / 128, NBATCH * NHEAD);  // (16, 32)
  attn_fwd<<<gA, 256, 0, stream>>>(Qb, Kb, Vb, Xa);

  gemm_bt<2><<<gQK, 256, 0, stream>>>(Xa, Wob, bo, (float*)d_out, MD, 1.0f);
  (void)in_sizes; (void)n_in; (void)out_size; (void)ws_size;
}

// Round 2
// 217.826 us; speedup vs baseline: 1.1835x; 1.1835x over previous
//
#include <hip/hip_runtime.h>

#define SEQ    2048
#define NBATCH 2
#define NHEAD  16
#define HD     64
#define MD     1024
#define TOK    (SEQ * NBATCH)   // 4096
#define XN8    (TOK * MD / 8)   // 524288 = 2^19
#define WN8    (MD * MD / 8)    // 131072 = 2^17

typedef __attribute__((ext_vector_type(4))) float f32x4;
typedef __attribute__((ext_vector_type(8))) short bf16x8;
typedef __attribute__((ext_vector_type(8))) unsigned short u16x8;

__device__ __forceinline__ unsigned short f2bf(float f) {
  union { float f; unsigned int u; } x; x.f = f;
  unsigned int u = x.u + 0x7fffu + ((x.u >> 16) & 1u);   // RNE; inputs are finite
  return (unsigned short)(u >> 16);
}

__device__ __forceinline__ void gload_lds16(const void* g, void* l) {
  typedef const __attribute__((address_space(1))) unsigned int* gp_t;
  typedef __attribute__((address_space(3))) unsigned int* lp_t;
  __builtin_amdgcn_global_load_lds((gp_t)g, (lp_t)l, 16, 0, 0);
}

// -------- fp32 -> bf16 convert, all 7 tensors in one launch --------------
__global__ __launch_bounds__(256) void cvt_all(
    const float* __restrict__ q, const float* __restrict__ k, const float* __restrict__ v,
    const float* __restrict__ wq, const float* __restrict__ wk,
    const float* __restrict__ wv, const float* __restrict__ wo,
    unsigned short* __restrict__ oq, unsigned short* __restrict__ ok,
    unsigned short* __restrict__ ov, unsigned short* __restrict__ owq,
    unsigned short* __restrict__ owk, unsigned short* __restrict__ owv,
    unsigned short* __restrict__ owo) {
  const int i = blockIdx.x * 256 + threadIdx.x;
  const float* src; unsigned short* dst; int r;
  if (i < 3 * XN8) {                 // boundaries 256-aligned: no divergence
    const int s = i >> 19; r = i & (XN8 - 1);
    src = s == 0 ? q : (s == 1 ? k : v);
    dst = s == 0 ? oq : (s == 1 ? ok : ov);
  } else {
    const int j = i - 3 * XN8; const int s = j >> 17; r = j & (WN8 - 1);
    src = s == 0 ? wq : (s == 1 ? wk : (s == 2 ? wv : wo));
    dst = s == 0 ? owq : (s == 1 ? owk : (s == 2 ? owv : owo));
  }
  const float4* p = (const float4*)src + (size_t)r * 2;
  float4 a = p[0];
  float4 b = p[1];
  u16x8 o;
  o[0] = f2bf(a.x); o[1] = f2bf(a.y); o[2] = f2bf(a.z); o[3] = f2bf(a.w);
  o[4] = f2bf(b.x); o[5] = f2bf(b.y); o[6] = f2bf(b.z); o[7] = f2bf(b.w);
  *((u16x8*)dst + r) = o;
}

// ------------- GEMM: C[M,N] = A[M,K] @ B[N,K]^T + bias ----------------
// 128x128 tile, BK=32, 8 waves (2Mx4N), global_load_lds w16, 512 threads.
// MODE 0: bf16 out scattered to [B,H,S,D]; val = (acc + bias[col]) * scale
// MODE 1: bf16 out scattered to [B,H,D,S]; rows are channels (A = weight)
// MODE 2: fp32 out row-major [M, MD];      val = acc + bias[col]
template <int MODE>
__global__ __launch_bounds__(512) void gemm_bt(const unsigned short* __restrict__ A,
                                               const unsigned short* __restrict__ B,
                                               const float* __restrict__ bias,
                                               void* __restrict__ Cout,
                                               int K, float scale) {
  __shared__ unsigned short sA[128 * 32];
  __shared__ unsigned short sB[128 * 32];
  const int tid  = threadIdx.x;
  const int lane = tid & 63;
  const int wave = tid >> 6;            // 0..7
  const int wm   = (wave >> 2) << 6;    // 2 M-waves x 64
  const int wn   = (wave & 3) << 5;     // 4 N-waves x 32
  const int l15  = lane & 15;
  const int g    = lane >> 4;
  const int bM   = blockIdx.y << 7;
  const int bN   = blockIdx.x << 7;

  f32x4 acc[4][2];
#pragma unroll
  for (int a_ = 0; a_ < 4; ++a_)
#pragma unroll
    for (int b_ = 0; b_ < 2; ++b_)
      acc[a_][b_] = f32x4{0.f, 0.f, 0.f, 0.f};

  const int r = tid >> 2, cc = tid & 3;   // 512 chunks each for sA, sB

  const int nk = K >> 5;
  for (int kt = 0; kt < nk; ++kt) {
    const int k0 = kt << 5;
    gload_lds16(A + (size_t)(bM + r) * K + k0 + cc * 8, (char*)sA + tid * 16);
    gload_lds16(B + (size_t)(bN + r) * K + k0 + cc * 8, (char*)sB + tid * 16);
    __syncthreads();
    bf16x8 af[4], bfr[2];
#pragma unroll
    for (int f = 0; f < 4; ++f)
      af[f] = *(const bf16x8*)&sA[(wm + f * 16 + l15) * 32 + g * 8];
#pragma unroll
    for (int f = 0; f < 2; ++f)
      bfr[f] = *(const bf16x8*)&sB[(wn + f * 16 + l15) * 32 + g * 8];
#pragma unroll
    for (int mf = 0; mf < 4; ++mf)
#pragma unroll
      for (int nf = 0; nf < 2; ++nf)
        acc[mf][nf] = __builtin_amdgcn_mfma_f32_16x16x32_bf16(af[mf], bfr[nf], acc[mf][nf], 0, 0, 0);
    __syncthreads();
  }

  if constexpr (MODE == 0) {
    unsigned short* O = (unsigned short*)Cout;
#pragma unroll
    for (int nf = 0; nf < 2; ++nf) {
      const int cch = bN + wn + nf * 16 + l15;
      const float bb = bias[cch];
      const int h = cch >> 6, d = cch & 63;
#pragma unroll
      for (int mf = 0; mf < 4; ++mf)
#pragma unroll
        for (int i = 0; i < 4; ++i) {
          const int t = bM + wm + mf * 16 + (g << 2) + i;
          const int b = t & 1, s = t >> 1;
          O[((((b << 4) + h) * SEQ + s) << 6) + d] = f2bf((acc[mf][nf][i] + bb) * scale);
        }
    }
  } else if constexpr (MODE == 1) {
    unsigned short* O = (unsigned short*)Cout;
#pragma unroll
    for (int mf = 0; mf < 4; ++mf)
#pragma unroll
      for (int i = 0; i < 4; ++i) {
        const int rch = bM + wm + mf * 16 + (g << 2) + i;
        const float bb = bias[rch];
        const int h = rch >> 6, d = rch & 63;
#pragma unroll
        for (int nf = 0; nf < 2; ++nf) {
          const int t = bN + wn + nf * 16 + l15;
          const int b = t & 1, s = t >> 1;
          O[((((b << 4) + h) << 6) + d) * SEQ + s] = f2bf(acc[mf][nf][i] + bb);
        }
      }
  } else {
    float* O = (float*)Cout;
#pragma unroll
    for (int nf = 0; nf < 2; ++nf) {
      const int cch = bN + wn + nf * 16 + l15;
      const float bb = bias[cch];
#pragma unroll
      for (int mf = 0; mf < 4; ++mf)
#pragma unroll
        for (int i = 0; i < 4; ++i) {
          const int t = bM + wm + mf * 16 + (g << 2) + i;
          O[(size_t)t * MD + cch] = acc[mf][nf][i] + bb;
        }
    }
  }
}

// --------------------- flash attention forward -------------------------
// grid: (SEQ/64, NBATCH*NHEAD) = 1024 blocks; 4 waves x 16 q-rows; KV tile 64.
// Q: [B,H,S,D] bf16 (pre-scaled by log2e/8 -> softmax in base-2 domain),
// K: [B,H,S,D], V: [B,H,D,S] bf16. Out: token-major [TOK, MD] bf16.
__global__ __launch_bounds__(256) void attn_fwd(const unsigned short* __restrict__ Qg,
                                                const unsigned short* __restrict__ Kg,
                                                const unsigned short* __restrict__ Vg,
                                                unsigned short* __restrict__ Xout) {
  __shared__ unsigned short sK[64 * 64];   // [k][d], XOR-swizzled
  __shared__ unsigned short sV[64 * 64];   // [d][k], XOR-swizzled
  __shared__ unsigned short sP[64 * 64];   // [q][k], XOR-swizzled

  const int tid  = threadIdx.x;
  const int lane = tid & 63;
  const int wave = tid >> 6;
  const int l15  = lane & 15;
  const int g    = lane >> 4;
  const int bh   = blockIdx.y;
  const int q0   = blockIdx.x << 6;
  const int wq   = wave << 4;              // 16 q-rows per wave

  const unsigned short* Qb = Qg + (size_t)bh * (SEQ * HD);
  const unsigned short* Kb = Kg + (size_t)bh * (SEQ * HD);
  const unsigned short* Vb = Vg + (size_t)bh * (HD * SEQ);

  bf16x8 qf[2];
#pragma unroll
  for (int ks = 0; ks < 2; ++ks)
    qf[ks] = *(const bf16x8*)&Qb[(size_t)(q0 + wq + l15) * HD + ks * 32 + g * 8];

  f32x4 acc_o[4];
  float mrow[4], lrow[4];
#pragma unroll
  for (int i = 0; i < 4; ++i) { mrow[i] = -1e30f; lrow[i] = 0.f; }
#pragma unroll
  for (int nf = 0; nf < 4; ++nf) acc_o[nf] = f32x4{0.f, 0.f, 0.f, 0.f};

  for (int kt = 0; kt < SEQ / 64; ++kt) {
    const int k0 = kt << 6;
    // stage K [64 k][64 d] and V^T [64 d][64 k]: linear LDS dest,
    // inverse-swizzled global source (swizzle: byte ^= (row&7)<<4)
#pragma unroll
    for (int j = 0; j < 2; ++j) {
      const int c = tid + (j << 8);
      const int p = c << 4;
      const int row = p >> 7;
      const int lcol = (p ^ ((row & 7) << 4)) & 127;
      gload_lds16((const char*)Kb + (size_t)(k0 + row) * (HD * 2) + lcol, (char*)sK + p);
      gload_lds16((const char*)Vb + (size_t)row * (SEQ * 2) + (k0 << 1) + lcol, (char*)sV + p);
    }
    __syncthreads();

    // S = Q K^T (log2e * scale folded into Q)
    f32x4 accs[4];
#pragma unroll
    for (int nf = 0; nf < 4; ++nf) accs[nf] = f32x4{0.f, 0.f, 0.f, 0.f};
    bf16x8 kf[4][2];
#pragma unroll
    for (int nf = 0; nf < 4; ++nf) {
      const int row = nf * 16 + l15;
#pragma unroll
      for (int ks = 0; ks < 2; ++ks) {
        const int off = ((row << 7) + ((ks * 32 + g * 8) << 1)) ^ ((row & 7) << 4);
        kf[nf][ks] = *(const bf16x8*)((const char*)sK + off);
      }
    }
#pragma unroll
    for (int nf = 0; nf < 4; ++nf)
#pragma unroll
      for (int ks = 0; ks < 2; ++ks)
        accs[nf] = __builtin_amdgcn_mfma_f32_16x16x32_bf16(qf[ks], kf[nf][ks], accs[nf], 0, 0, 0);

    // online softmax (base-2). lrow is a per-lane PARTIAL sum: the rescale
    // factor is row-uniform (derived from the shfl-reduced max), so the
    // 16-lane row sum is deferred to the epilogue.
#pragma unroll
    for (int i = 0; i < 4; ++i) {
      float mx = fmaxf(fmaxf(accs[0][i], accs[1][i]), fmaxf(accs[2][i], accs[3][i]));
      mx = fmaxf(mx, __shfl_xor(mx, 1));
      mx = fmaxf(mx, __shfl_xor(mx, 2));
      mx = fmaxf(mx, __shfl_xor(mx, 4));
      mx = fmaxf(mx, __shfl_xor(mx, 8));
      const float mold = mrow[i];
      const float mnew = fmaxf(mold, mx);
      const float resc = __builtin_amdgcn_exp2f(mold - mnew);
      mrow[i] = mnew;
      float rsum = 0.f;
#pragma unroll
      for (int nf = 0; nf < 4; ++nf) {
        const float pv = __builtin_amdgcn_exp2f(accs[nf][i] - mnew);
        accs[nf][i] = pv;
        rsum += pv;
      }
      lrow[i] = lrow[i] * resc + rsum;
#pragma unroll
      for (int nf = 0; nf < 4; ++nf) acc_o[nf][i] *= resc;
    }

    // P (C-layout) -> LDS bf16, swizzled. Same-wave producer/consumer.
#pragma unroll
    for (int nf = 0; nf < 4; ++nf)
#pragma unroll
      for (int i = 0; i < 4; ++i) {
        const int qr = wq + (g << 2) + i;
        const int kc = nf * 16 + l15;
        const int off = ((qr << 7) + (kc << 1)) ^ ((qr & 7) << 4);
        *(unsigned short*)((char*)sP + off) = f2bf(accs[nf][i]);
      }
    asm volatile("s_waitcnt lgkmcnt(0)" ::: "memory");

    // O += P V  (A = P rows, B = V^T rows)
    bf16x8 pf[2], vf[4][2];
#pragma unroll
    for (int ks = 0; ks < 2; ++ks) {
      const int qr = wq + l15;
      const int off = ((qr << 7) + ((ks * 32 + g * 8) << 1)) ^ ((qr & 7) << 4);
      pf[ks] = *(const bf16x8*)((const char*)sP + off);
    }
#pragma unroll
    for (int nf = 0; nf < 4; ++nf)
#pragma unroll
      for (int ks = 0; ks < 2; ++ks) {
        const int dr = nf * 16 + l15;
        const int off = ((dr << 7) + ((ks * 32 + g * 8) << 1)) ^ ((dr & 7) << 4);
        vf[nf][ks] = *(const bf16x8*)((const char*)sV + off);
      }
#pragma unroll
    for (int nf = 0; nf < 4; ++nf)
#pragma unroll
      for (int ks = 0; ks < 2; ++ks)
        acc_o[nf] = __builtin_amdgcn_mfma_f32_16x16x32_bf16(pf[ks], vf[nf][ks], acc_o[nf], 0, 0, 0);

    __syncthreads();
  }

  // epilogue: finish the deferred 16-lane row sum, then x[t, h*64+d] = O / l
  const int b = bh >> 4, h = bh & 15;
#pragma unroll
  for (int i = 0; i < 4; ++i) {
    float l = lrow[i];
    l += __shfl_xor(l, 1);
    l += __shfl_xor(l, 2);
    l += __shfl_xor(l, 4);
    l += __shfl_xor(l, 8);
    const float inv = 1.f / l;
    const int s = q0 + wq + (g << 2) + i;
    const int t = s * NBATCH + b;
#pragma unroll
    for (int nf = 0; nf < 4; ++nf) {
      const int col = (h << 6) + nf * 16 + l15;
      Xout[(size_t)t * MD + col] = f2bf(acc_o[nf][i] * inv);
    }
  }
}

extern "C" void kernel_launch(void* const* d_in, const int* in_sizes, int n_in,
                              void* d_out, int out_size, void* d_ws, size_t ws_size,
                              hipStream_t stream) {
  const float* query = (const float*)d_in[0];
  const float* key   = (const float*)d_in[1];
  const float* value = (const float*)d_in[2];
  // d_in[3] = mask: dead code in reference
  const float* Wq = (const float*)d_in[4];
  const float* bq = (const float*)d_in[5];
  const float* Wk = (const float*)d_in[6];
  const float* bk = (const float*)d_in[7];
  const float* Wv = (const float*)d_in[8];
  const float* bv = (const float*)d_in[9];
  const float* Wo = (const float*)d_in[10];
  const float* bo = (const float*)d_in[11];

  char* ws = (char*)d_ws;
  const size_t MB = 1024 * 1024;
  unsigned short* Xq  = (unsigned short*)(ws + 0 * MB);   // [TOK,MD] bf16
  unsigned short* Xk  = (unsigned short*)(ws + 8 * MB);
  unsigned short* Xv  = (unsigned short*)(ws + 16 * MB);
  unsigned short* Wqb = (unsigned short*)(ws + 24 * MB);
  unsigned short* Wkb = (unsigned short*)(ws + 26 * MB);
  unsigned short* Wvb = (unsigned short*)(ws + 28 * MB);
  unsigned short* Wob = (unsigned short*)(ws + 30 * MB);
  unsigned short* Qb  = (unsigned short*)(ws + 32 * MB);  // [B,H,S,D]
  unsigned short* Kb  = (unsigned short*)(ws + 40 * MB);  // [B,H,S,D]
  unsigned short* Vb  = (unsigned short*)(ws + 48 * MB);  // [B,H,D,S]
  unsigned short* Xa  = Xq;  // alias: Xq dead after Q projection

  cvt_all<<<(3 * XN8 + 4 * WN8) / 256, 256, 0, stream>>>(
      query, key, value, Wq, Wk, Wv, Wo, Xq, Xk, Xv, Wqb, Wkb, Wvb, Wob);

  const float kQScale = 0.125f * 1.44269504088896340736f;  // (1/sqrt(64))*log2(e)
  dim3 gQK(MD / 128, TOK / 128);   // (8, 32)
  gemm_bt<0><<<gQK, 512, 0, stream>>>(Xq, Wqb, bq, Qb, MD, kQScale);
  gemm_bt<0><<<gQK, 512, 0, stream>>>(Xk, Wkb, bk, Kb, MD, 1.0f);
  dim3 gV(TOK / 128, MD / 128);    // (32, 8): swapped operands -> V^T out
  gemm_bt<1><<<gV, 512, 0, stream>>>(Wvb, Xv, bv, Vb, MD, 1.0f);

  dim3 gA(SEQ / 64, NBATCH * NHEAD);  // (32, 32)
  attn_fwd<<<gA, 256, 0, stream>>>(Qb, Kb, Vb, Xa);

  gemm_bt<2><<<gQK, 512, 0, stream>>>(Xa, Wob, bo, (float*)d_out, MD, 1.0f);
  (void)in_sizes; (void)n_in; (void)out_size; (void)ws_size;
}

// Round 3
// 191.384 us; speedup vs baseline: 1.3470x; 1.1382x over previous
//
#include <hip/hip_runtime.h>

#define SEQ    2048
#define NBATCH 2
#define NHEAD  16
#define HD     64
#define MD     1024
#define TOK    (SEQ * NBATCH)   // 4096
#define XN8    (TOK * MD / 8)   // 524288 = 2^19
#define WN8    (MD * MD / 8)    // 131072 = 2^17

typedef __attribute__((ext_vector_type(4))) float f32x4;
typedef __attribute__((ext_vector_type(8))) short bf16x8;
typedef __attribute__((ext_vector_type(8))) unsigned short u16x8;

__device__ __forceinline__ unsigned short f2bf(float f) {
  union { float f; unsigned int u; } x; x.f = f;
  unsigned int u = x.u + 0x7fffu + ((x.u >> 16) & 1u);   // RNE; inputs are finite
  return (unsigned short)(u >> 16);
}

__device__ __forceinline__ void gload_lds16(const void* g, void* l) {
  typedef const __attribute__((address_space(1))) unsigned int* gp_t;
  typedef __attribute__((address_space(3))) unsigned int* lp_t;
  __builtin_amdgcn_global_load_lds((gp_t)g, (lp_t)l, 16, 0, 0);
}

// -------- fp32 -> bf16 convert, all 7 tensors in one launch --------------
__global__ __launch_bounds__(256) void cvt_all(
    const float* __restrict__ q, const float* __restrict__ k, const float* __restrict__ v,
    const float* __restrict__ wq, const float* __restrict__ wk,
    const float* __restrict__ wv, const float* __restrict__ wo,
    unsigned short* __restrict__ oq, unsigned short* __restrict__ ok,
    unsigned short* __restrict__ ov, unsigned short* __restrict__ owq,
    unsigned short* __restrict__ owk, unsigned short* __restrict__ owv,
    unsigned short* __restrict__ owo) {
  const int i = blockIdx.x * 256 + threadIdx.x;
  const float* src; unsigned short* dst; int r;
  if (i < 3 * XN8) {                 // boundaries 256-aligned: no divergence
    const int s = i >> 19; r = i & (XN8 - 1);
    src = s == 0 ? q : (s == 1 ? k : v);
    dst = s == 0 ? oq : (s == 1 ? ok : ov);
  } else {
    const int j = i - 3 * XN8; const int s = j >> 17; r = j & (WN8 - 1);
    src = s == 0 ? wq : (s == 1 ? wk : (s == 2 ? wv : wo));
    dst = s == 0 ? owq : (s == 1 ? owk : (s == 2 ? owv : owo));
  }
  const float4* p = (const float4*)src + (size_t)r * 2;
  float4 a = p[0];
  float4 b = p[1];
  u16x8 o;
  o[0] = f2bf(a.x); o[1] = f2bf(a.y); o[2] = f2bf(a.z); o[3] = f2bf(a.w);
  o[4] = f2bf(b.x); o[5] = f2bf(b.y); o[6] = f2bf(b.z); o[7] = f2bf(b.w);
  *((u16x8*)dst + r) = o;
}

// ---- fused QKV projection: grid (8, 32, 3), 128x128 tile, 8 waves ------
// z=0: Q = Xq@Wq^T+bq -> [B,H,S,D] * qscale   (mode 0)
// z=1: K = Xk@Wk^T+bk -> [B,H,S,D]            (mode 0)
// z=2: V^T: A=Wv, B=Xv -> [B,H,D,S]           (mode 1)
// Double-buffered LDS, prefetch-before-compute (T3 2-phase).
__global__ __launch_bounds__(512) void gemm_qkv(
    const unsigned short* __restrict__ Xq, const unsigned short* __restrict__ Xk,
    const unsigned short* __restrict__ Xv, const unsigned short* __restrict__ Wq,
    const unsigned short* __restrict__ Wk, const unsigned short* __restrict__ Wv,
    const float* __restrict__ bq, const float* __restrict__ bk, const float* __restrict__ bv,
    unsigned short* __restrict__ Qo, unsigned short* __restrict__ Ko,
    unsigned short* __restrict__ Vo, float qscale) {
  __shared__ unsigned short sA[2][128 * 32];
  __shared__ unsigned short sB[2][128 * 32];
  const int tid  = threadIdx.x;
  const int lane = tid & 63;
  const int wave = tid >> 6;            // 0..7
  const int wm   = (wave >> 2) << 6;    // 2 M-waves x 64
  const int wn   = (wave & 3) << 5;     // 4 N-waves x 32
  const int l15  = lane & 15;
  const int g    = lane >> 4;
  const int z    = blockIdx.z;

  const unsigned short* A; const unsigned short* B; const float* bias;
  int bM, bN;
  if (z == 0)      { A = Xq; B = Wq; bias = bq; }
  else if (z == 1) { A = Xk; B = Wk; bias = bk; }
  else             { A = Wv; B = Xv; bias = bv; }
  if (z < 2) { bM = blockIdx.y << 7; bN = blockIdx.x << 7; }
  else       { bM = blockIdx.x << 7; bN = blockIdx.y << 7; }

  f32x4 acc[4][2];
#pragma unroll
  for (int a_ = 0; a_ < 4; ++a_)
#pragma unroll
    for (int b_ = 0; b_ < 2; ++b_)
      acc[a_][b_] = f32x4{0.f, 0.f, 0.f, 0.f};

  const int r = tid >> 2, cc = tid & 3;

  auto stage = [&](int c, int kt) {
    const int k0 = kt << 5;
    gload_lds16(A + (size_t)(bM + r) * MD + k0 + cc * 8, (char*)sA[c] + tid * 16);
    gload_lds16(B + (size_t)(bN + r) * MD + k0 + cc * 8, (char*)sB[c] + tid * 16);
  };

  stage(0, 0);
  __syncthreads();                      // compiler drains vmcnt(0) here
  int cur = 0;
  const int nk = MD >> 5;
  for (int kt = 0; kt < nk; ++kt) {
    if (kt + 1 < nk) stage(cur ^ 1, kt + 1);   // prefetch overlaps compute
    bf16x8 af[4], bfr[2];
#pragma unroll
    for (int f = 0; f < 4; ++f)
      af[f] = *(const bf16x8*)&sA[cur][(wm + f * 16 + l15) * 32 + g * 8];
#pragma unroll
    for (int f = 0; f < 2; ++f)
      bfr[f] = *(const bf16x8*)&sB[cur][(wn + f * 16 + l15) * 32 + g * 8];
#pragma unroll
    for (int mf = 0; mf < 4; ++mf)
#pragma unroll
      for (int nf = 0; nf < 2; ++nf)
        acc[mf][nf] = __builtin_amdgcn_mfma_f32_16x16x32_bf16(af[mf], bfr[nf], acc[mf][nf], 0, 0, 0);
    __syncthreads();
    cur ^= 1;
  }

  if (z < 2) {
    unsigned short* O = (z == 0) ? Qo : Ko;
    const float scale = (z == 0) ? qscale : 1.0f;
#pragma unroll
    for (int nf = 0; nf < 2; ++nf) {
      const int cch = bN + wn + nf * 16 + l15;
      const float bb = bias[cch];
      const int h = cch >> 6, d = cch & 63;
#pragma unroll
      for (int mf = 0; mf < 4; ++mf)
#pragma unroll
        for (int i = 0; i < 4; ++i) {
          const int t = bM + wm + mf * 16 + (g << 2) + i;
          const int b = t & 1, s = t >> 1;
          O[((((b << 4) + h) * SEQ + s) << 6) + d] = f2bf((acc[mf][nf][i] + bb) * scale);
        }
    }
  } else {
#pragma unroll
    for (int mf = 0; mf < 4; ++mf)
#pragma unroll
      for (int i = 0; i < 4; ++i) {
        const int rch = bM + wm + mf * 16 + (g << 2) + i;
        const float bb = bias[rch];
        const int h = rch >> 6, d = rch & 63;
#pragma unroll
        for (int nf = 0; nf < 2; ++nf) {
          const int t = bN + wn + nf * 16 + l15;
          const int b = t & 1, s = t >> 1;
          Vo[((((b << 4) + h) << 6) + d) * SEQ + s] = f2bf(acc[mf][nf][i] + bb);
        }
      }
  }
}

// ---------------- O projection: fp32 out, double-buffered ----------------
__global__ __launch_bounds__(512) void gemm_oproj(const unsigned short* __restrict__ A,
                                                  const unsigned short* __restrict__ B,
                                                  const float* __restrict__ bias,
                                                  float* __restrict__ O) {
  __shared__ unsigned short sA[2][128 * 32];
  __shared__ unsigned short sB[2][128 * 32];
  const int tid  = threadIdx.x;
  const int lane = tid & 63;
  const int wave = tid >> 6;
  const int wm   = (wave >> 2) << 6;
  const int wn   = (wave & 3) << 5;
  const int l15  = lane & 15;
  const int g    = lane >> 4;
  const int bM   = blockIdx.y << 7;
  const int bN   = blockIdx.x << 7;

  f32x4 acc[4][2];
#pragma unroll
  for (int a_ = 0; a_ < 4; ++a_)
#pragma unroll
    for (int b_ = 0; b_ < 2; ++b_)
      acc[a_][b_] = f32x4{0.f, 0.f, 0.f, 0.f};

  const int r = tid >> 2, cc = tid & 3;
  auto stage = [&](int c, int kt) {
    const int k0 = kt << 5;
    gload_lds16(A + (size_t)(bM + r) * MD + k0 + cc * 8, (char*)sA[c] + tid * 16);
    gload_lds16(B + (size_t)(bN + r) * MD + k0 + cc * 8, (char*)sB[c] + tid * 16);
  };

  stage(0, 0);
  __syncthreads();
  int cur = 0;
  const int nk = MD >> 5;
  for (int kt = 0; kt < nk; ++kt) {
    if (kt + 1 < nk) stage(cur ^ 1, kt + 1);
    bf16x8 af[4], bfr[2];
#pragma unroll
    for (int f = 0; f < 4; ++f)
      af[f] = *(const bf16x8*)&sA[cur][(wm + f * 16 + l15) * 32 + g * 8];
#pragma unroll
    for (int f = 0; f < 2; ++f)
      bfr[f] = *(const bf16x8*)&sB[cur][(wn + f * 16 + l15) * 32 + g * 8];
#pragma unroll
    for (int mf = 0; mf < 4; ++mf)
#pragma unroll
      for (int nf = 0; nf < 2; ++nf)
        acc[mf][nf] = __builtin_amdgcn_mfma_f32_16x16x32_bf16(af[mf], bfr[nf], acc[mf][nf], 0, 0, 0);
    __syncthreads();
    cur ^= 1;
  }

#pragma unroll
  for (int nf = 0; nf < 2; ++nf) {
    const int cch = bN + wn + nf * 16 + l15;
    const float bb = bias[cch];
#pragma unroll
    for (int mf = 0; mf < 4; ++mf)
#pragma unroll
      for (int i = 0; i < 4; ++i) {
        const int t = bM + wm + mf * 16 + (g << 2) + i;
        O[(size_t)t * MD + cch] = acc[mf][nf][i] + bb;
      }
  }
}

// --------------------- flash attention forward -------------------------
// grid: (SEQ/64, NBATCH*NHEAD) = 1024 blocks; 4 waves x 16 q-rows; KV tile 64.
// Double-buffered K/V staging: prefetch tile t+1 before computing tile t.
// Q: [B,H,S,D] bf16 (pre-scaled by log2e/8), K: [B,H,S,D], V: [B,H,D,S].
// Out: token-major [TOK, MD] bf16.  LDS = 40960 B -> 4 blocks/CU exactly.
__global__ __launch_bounds__(256) void attn_fwd(const unsigned short* __restrict__ Qg,
                                                const unsigned short* __restrict__ Kg,
                                                const unsigned short* __restrict__ Vg,
                                                unsigned short* __restrict__ Xout) {
  __shared__ unsigned short sK[2][64 * 64];  // [k][d], XOR-swizzled
  __shared__ unsigned short sV[2][64 * 64];  // [d][k], XOR-swizzled
  __shared__ unsigned short sP[64 * 64];     // [q][k], XOR-swizzled

  const int tid  = threadIdx.x;
  const int lane = tid & 63;
  const int wave = tid >> 6;
  const int l15  = lane & 15;
  const int g    = lane >> 4;
  const int bh   = blockIdx.y;
  const int q0   = blockIdx.x << 6;
  const int wq   = wave << 4;              // 16 q-rows per wave

  const unsigned short* Qb = Qg + (size_t)bh * (SEQ * HD);
  const unsigned short* Kb = Kg + (size_t)bh * (SEQ * HD);
  const unsigned short* Vb = Vg + (size_t)bh * (HD * SEQ);

  bf16x8 qf[2];
#pragma unroll
  for (int ks = 0; ks < 2; ++ks)
    qf[ks] = *(const bf16x8*)&Qb[(size_t)(q0 + wq + l15) * HD + ks * 32 + g * 8];

  f32x4 acc_o[4];
  float mrow[4], lrow[4];
#pragma unroll
  for (int i = 0; i < 4; ++i) { mrow[i] = -1e30f; lrow[i] = 0.f; }
#pragma unroll
  for (int nf = 0; nf < 4; ++nf) acc_o[nf] = f32x4{0.f, 0.f, 0.f, 0.f};

  // stage K [64 k][64 d] and V^T [64 d][64 k] into buffer c: linear LDS
  // dest, inverse-swizzled global source (swizzle: byte ^= (row&7)<<4)
  auto stage = [&](int c, int kt) {
    const int k0 = kt << 6;
#pragma unroll
    for (int j = 0; j < 2; ++j) {
      const int p = (tid + (j << 8)) << 4;
      const int row = p >> 7;
      const int lcol = (p ^ ((row & 7) << 4)) & 127;
      gload_lds16((const char*)Kb + (size_t)(k0 + row) * (HD * 2) + lcol, (char*)sK[c] + p);
      gload_lds16((const char*)Vb + (size_t)row * (SEQ * 2) + (k0 << 1) + lcol, (char*)sV[c] + p);
    }
  };

  stage(0, 0);
  __syncthreads();                         // vmcnt(0) drained by compiler
  int cur = 0;

  for (int kt = 0; kt < SEQ / 64; ++kt) {
    if (kt + 1 < SEQ / 64) stage(cur ^ 1, kt + 1);   // prefetch next tile

    // S = Q K^T (log2e * scale folded into Q)
    f32x4 accs[4];
#pragma unroll
    for (int nf = 0; nf < 4; ++nf) accs[nf] = f32x4{0.f, 0.f, 0.f, 0.f};
    bf16x8 kf[4][2];
#pragma unroll
    for (int nf = 0; nf < 4; ++nf) {
      const int row = nf * 16 + l15;
#pragma unroll
      for (int ks = 0; ks < 2; ++ks) {
        const int off = ((row << 7) + ((ks * 32 + g * 8) << 1)) ^ ((row & 7) << 4);
        kf[nf][ks] = *(const bf16x8*)((const char*)sK[cur] + off);
      }
    }
#pragma unroll
    for (int nf = 0; nf < 4; ++nf)
#pragma unroll
      for (int ks = 0; ks < 2; ++ks)
        accs[nf] = __builtin_amdgcn_mfma_f32_16x16x32_bf16(qf[ks], kf[nf][ks], accs[nf], 0, 0, 0);

    // online softmax (base-2); lrow is per-lane partial, reduced in epilogue
#pragma unroll
    for (int i = 0; i < 4; ++i) {
      float mx = fmaxf(fmaxf(accs[0][i], accs[1][i]), fmaxf(accs[2][i], accs[3][i]));
      mx = fmaxf(mx, __shfl_xor(mx, 1));
      mx = fmaxf(mx, __shfl_xor(mx, 2));
      mx = fmaxf(mx, __shfl_xor(mx, 4));
      mx = fmaxf(mx, __shfl_xor(mx, 8));
      const float mold = mrow[i];
      const float mnew = fmaxf(mold, mx);
      const float resc = __builtin_amdgcn_exp2f(mold - mnew);
      mrow[i] = mnew;
      float rsum = 0.f;
#pragma unroll
      for (int nf = 0; nf < 4; ++nf) {
        const float pv = __builtin_amdgcn_exp2f(accs[nf][i] - mnew);
        accs[nf][i] = pv;
        rsum += pv;
      }
      lrow[i] = lrow[i] * resc + rsum;
#pragma unroll
      for (int nf = 0; nf < 4; ++nf) acc_o[nf][i] *= resc;
    }

    // P (C-layout) -> LDS bf16, swizzled. Same-wave producer/consumer.
#pragma unroll
    for (int nf = 0; nf < 4; ++nf)
#pragma unroll
      for (int i = 0; i < 4; ++i) {
        const int qr = wq + (g << 2) + i;
        const int kc = nf * 16 + l15;
        const int off = ((qr << 7) + (kc << 1)) ^ ((qr & 7) << 4);
        *(unsigned short*)((char*)sP + off) = f2bf(accs[nf][i]);
      }
    asm volatile("s_waitcnt lgkmcnt(0)" ::: "memory");

    // O += P V  (A = P rows, B = V^T rows)
    bf16x8 pf[2], vf[4][2];
#pragma unroll
    for (int ks = 0; ks < 2; ++ks) {
      const int qr = wq + l15;
      const int off = ((qr << 7) + ((ks * 32 + g * 8) << 1)) ^ ((qr & 7) << 4);
      pf[ks] = *(const bf16x8*)((const char*)sP + off);
    }
#pragma unroll
    for (int nf = 0; nf < 4; ++nf)
#pragma unroll
      for (int ks = 0; ks < 2; ++ks) {
        const int dr = nf * 16 + l15;
        const int off = ((dr << 7) + ((ks * 32 + g * 8) << 1)) ^ ((dr & 7) << 4);
        vf[nf][ks] = *(const bf16x8*)((const char*)sV[cur] + off);
      }
#pragma unroll
    for (int nf = 0; nf < 4; ++nf)
#pragma unroll
      for (int ks = 0; ks < 2; ++ks)
        acc_o[nf] = __builtin_amdgcn_mfma_f32_16x16x32_bf16(pf[ks], vf[nf][ks], acc_o[nf], 0, 0, 0);

    __syncthreads();                       // next tile's loads also drained
    cur ^= 1;
  }

  // epilogue: finish deferred 16-lane row sum, then x[t, h*64+d] = O / l
  const int b = bh >> 4, h = bh & 15;
#pragma unroll
  for (int i = 0; i < 4; ++i) {
    float l = lrow[i];
    l += __shfl_xor(l, 1);
    l += __shfl_xor(l, 2);
    l += __shfl_xor(l, 4);
    l += __shfl_xor(l, 8);
    const float inv = 1.f / l;
    const int s = q0 + wq + (g << 2) + i;
    const int t = s * NBATCH + b;
#pragma unroll
    for (int nf = 0; nf < 4; ++nf) {
      const int col = (h << 6) + nf * 16 + l15;
      Xout[(size_t)t * MD + col] = f2bf(acc_o[nf][i] * inv);
    }
  }
}

extern "C" void kernel_launch(void* const* d_in, const int* in_sizes, int n_in,
                              void* d_out, int out_size, void* d_ws, size_t ws_size,
                              hipStream_t stream) {
  const float* query = (const float*)d_in[0];
  const float* key   = (const float*)d_in[1];
  const float* value = (const float*)d_in[2];
  // d_in[3] = mask: dead code in reference
  const float* Wq = (const float*)d_in[4];
  const float* bq = (const float*)d_in[5];
  const float* Wk = (const float*)d_in[6];
  const float* bk = (const float*)d_in[7];
  const float* Wv = (const float*)d_in[8];
  const float* bv = (const float*)d_in[9];
  const float* Wo = (const float*)d_in[10];
  const float* bo = (const float*)d_in[11];

  char* ws = (char*)d_ws;
  const size_t MB = 1024 * 1024;
  unsigned short* Xq  = (unsigned short*)(ws + 0 * MB);   // [TOK,MD] bf16
  unsigned short* Xk  = (unsigned short*)(ws + 8 * MB);
  unsigned short* Xv  = (unsigned short*)(ws + 16 * MB);
  unsigned short* Wqb = (unsigned short*)(ws + 24 * MB);
  unsigned short* Wkb = (unsigned short*)(ws + 26 * MB);
  unsigned short* Wvb = (unsigned short*)(ws + 28 * MB);
  unsigned short* Wob = (unsigned short*)(ws + 30 * MB);
  unsigned short* Qb  = (unsigned short*)(ws + 32 * MB);  // [B,H,S,D]
  unsigned short* Kb  = (unsigned short*)(ws + 40 * MB);  // [B,H,S,D]
  unsigned short* Vb  = (unsigned short*)(ws + 48 * MB);  // [B,H,D,S]
  unsigned short* Xa  = Xq;  // alias: Xq dead after Q projection

  cvt_all<<<(3 * XN8 + 4 * WN8) / 256, 256, 0, stream>>>(
      query, key, value, Wq, Wk, Wv, Wo, Xq, Xk, Xv, Wqb, Wkb, Wvb, Wob);

  const float kQScale = 0.125f * 1.44269504088896340736f;  // (1/sqrt(64))*log2(e)
  dim3 gQKV(MD / 128, TOK / 128, 3);   // (8, 32, 3) = 768 blocks
  gemm_qkv<<<gQKV, 512, 0, stream>>>(Xq, Xk, Xv, Wqb, Wkb, Wvb,
                                     bq, bk, bv, Qb, Kb, Vb, kQScale);

  dim3 gA(SEQ / 64, NBATCH * NHEAD);   // (32, 32) = 1024 blocks
  attn_fwd<<<gA, 256, 0, stream>>>(Qb, Kb, Vb, Xa);

  dim3 gO(MD / 128, TOK / 128);        // (8, 32)
  gemm_oproj<<<gO, 512, 0, stream>>>(Xa, Wob, bo, (float*)d_out);
  (void)in_sizes; (void)n_in; (void)out_size; (void)ws_size;
}

// Round 4
// 145.585 us; speedup vs baseline: 1.7707x; 1.3146x over previous
//
#include <hip/hip_runtime.h>

#define SEQ    2048
#define NBATCH 2
#define NHEAD  16
#define HD     64
#define MD     1024
#define TOK    (SEQ * NBATCH)   // 4096
#define XN8    (TOK * MD / 8)   // 524288 = 2^19
#define WN8    (MD * MD / 8)    // 131072 = 2^17

typedef __attribute__((ext_vector_type(4)))  float f32x4;
typedef __attribute__((ext_vector_type(16))) float f32x16;
typedef __attribute__((ext_vector_type(8)))  short bf16x8;
typedef __attribute__((ext_vector_type(8)))  unsigned short u16x8;

__device__ __forceinline__ unsigned short f2bf(float f) {
  union { float f; unsigned int u; } x; x.f = f;
  unsigned int u = x.u + 0x7fffu + ((x.u >> 16) & 1u);   // RNE; inputs are finite
  return (unsigned short)(u >> 16);
}

// v_cvt_pk_bf16_f32: D[15:0]=bf16(lo), D[31:16]=bf16(hi)  (no builtin on gfx950)
__device__ __forceinline__ unsigned cvtpk(float lo, float hi) {
  unsigned r;
  asm("v_cvt_pk_bf16_f32 %0, %1, %2" : "=v"(r) : "v"(lo), "v"(hi));
  return r;
}
// v_permlane32_swap_b32: a' = (a_lo | b_lo), b' = (a_hi | b_hi)
__device__ __forceinline__ void plswap(unsigned &a, unsigned &b) {
  asm volatile("v_permlane32_swap_b32 %0, %1" : "+v"(a), "+v"(b));
}

__device__ __forceinline__ void gload_lds16(const void* g, void* l) {
  typedef const __attribute__((address_space(1))) unsigned int* gp_t;
  typedef __attribute__((address_space(3))) unsigned int* lp_t;
  __builtin_amdgcn_global_load_lds((gp_t)g, (lp_t)l, 16, 0, 0);
}

// -------- fp32 -> bf16 convert, all 7 tensors in one launch --------------
__global__ __launch_bounds__(256) void cvt_all(
    const float* __restrict__ q, const float* __restrict__ k, const float* __restrict__ v,
    const float* __restrict__ wq, const float* __restrict__ wk,
    const float* __restrict__ wv, const float* __restrict__ wo,
    unsigned short* __restrict__ oq, unsigned short* __restrict__ ok,
    unsigned short* __restrict__ ov, unsigned short* __restrict__ owq,
    unsigned short* __restrict__ owk, unsigned short* __restrict__ owv,
    unsigned short* __restrict__ owo) {
  const int i = blockIdx.x * 256 + threadIdx.x;
  const float* src; unsigned short* dst; int r;
  if (i < 3 * XN8) {                 // boundaries 256-aligned: no divergence
    const int s = i >> 19; r = i & (XN8 - 1);
    src = s == 0 ? q : (s == 1 ? k : v);
    dst = s == 0 ? oq : (s == 1 ? ok : ov);
  } else {
    const int j = i - 3 * XN8; const int s = j >> 17; r = j & (WN8 - 1);
    src = s == 0 ? wq : (s == 1 ? wk : (s == 2 ? wv : wo));
    dst = s == 0 ? owq : (s == 1 ? owk : (s == 2 ? owv : owo));
  }
  const float4* p = (const float4*)src + (size_t)r * 2;
  float4 a = p[0];
  float4 b = p[1];
  u16x8 o;
  o[0] = f2bf(a.x); o[1] = f2bf(a.y); o[2] = f2bf(a.z); o[3] = f2bf(a.w);
  o[4] = f2bf(b.x); o[5] = f2bf(b.y); o[6] = f2bf(b.z); o[7] = f2bf(b.w);
  *((u16x8*)dst + r) = o;
}

// ---- fused QKV projection: grid (8, 32, 3), 128x128 tile, 8 waves ------
__global__ __launch_bounds__(512) void gemm_qkv(
    const unsigned short* __restrict__ Xq, const unsigned short* __restrict__ Xk,
    const unsigned short* __restrict__ Xv, const unsigned short* __restrict__ Wq,
    const unsigned short* __restrict__ Wk, const unsigned short* __restrict__ Wv,
    const float* __restrict__ bq, const float* __restrict__ bk, const float* __restrict__ bv,
    unsigned short* __restrict__ Qo, unsigned short* __restrict__ Ko,
    unsigned short* __restrict__ Vo, float qscale) {
  __shared__ unsigned short sA[2][128 * 32];
  __shared__ unsigned short sB[2][128 * 32];
  const int tid  = threadIdx.x;
  const int lane = tid & 63;
  const int wave = tid >> 6;            // 0..7
  const int wm   = (wave >> 2) << 6;    // 2 M-waves x 64
  const int wn   = (wave & 3) << 5;     // 4 N-waves x 32
  const int l15  = lane & 15;
  const int g    = lane >> 4;
  const int z    = blockIdx.z;

  const unsigned short* A; const unsigned short* B; const float* bias;
  int bM, bN;
  if (z == 0)      { A = Xq; B = Wq; bias = bq; }
  else if (z == 1) { A = Xk; B = Wk; bias = bk; }
  else             { A = Wv; B = Xv; bias = bv; }
  if (z < 2) { bM = blockIdx.y << 7; bN = blockIdx.x << 7; }
  else       { bM = blockIdx.x << 7; bN = blockIdx.y << 7; }

  f32x4 acc[4][2];
#pragma unroll
  for (int a_ = 0; a_ < 4; ++a_)
#pragma unroll
    for (int b_ = 0; b_ < 2; ++b_)
      acc[a_][b_] = f32x4{0.f, 0.f, 0.f, 0.f};

  const int r = tid >> 2, cc = tid & 3;

  auto stage = [&](int c, int kt) {
    const int k0 = kt << 5;
    gload_lds16(A + (size_t)(bM + r) * MD + k0 + cc * 8, (char*)sA[c] + tid * 16);
    gload_lds16(B + (size_t)(bN + r) * MD + k0 + cc * 8, (char*)sB[c] + tid * 16);
  };

  stage(0, 0);
  __syncthreads();
  int cur = 0;
  const int nk = MD >> 5;
  for (int kt = 0; kt < nk; ++kt) {
    if (kt + 1 < nk) stage(cur ^ 1, kt + 1);
    bf16x8 af[4], bfr[2];
#pragma unroll
    for (int f = 0; f < 4; ++f)
      af[f] = *(const bf16x8*)&sA[cur][(wm + f * 16 + l15) * 32 + g * 8];
#pragma unroll
    for (int f = 0; f < 2; ++f)
      bfr[f] = *(const bf16x8*)&sB[cur][(wn + f * 16 + l15) * 32 + g * 8];
#pragma unroll
    for (int mf = 0; mf < 4; ++mf)
#pragma unroll
      for (int nf = 0; nf < 2; ++nf)
        acc[mf][nf] = __builtin_amdgcn_mfma_f32_16x16x32_bf16(af[mf], bfr[nf], acc[mf][nf], 0, 0, 0);
    __syncthreads();
    cur ^= 1;
  }

  if (z < 2) {
    unsigned short* O = (z == 0) ? Qo : Ko;
    const float scale = (z == 0) ? qscale : 1.0f;
#pragma unroll
    for (int nf = 0; nf < 2; ++nf) {
      const int cch = bN + wn + nf * 16 + l15;
      const float bb = bias[cch];
      const int h = cch >> 6, d = cch & 63;
#pragma unroll
      for (int mf = 0; mf < 4; ++mf)
#pragma unroll
        for (int i = 0; i < 4; ++i) {
          const int t = bM + wm + mf * 16 + (g << 2) + i;
          const int b = t & 1, s = t >> 1;
          O[((((b << 4) + h) * SEQ + s) << 6) + d] = f2bf((acc[mf][nf][i] + bb) * scale);
        }
    }
  } else {
#pragma unroll
    for (int mf = 0; mf < 4; ++mf)
#pragma unroll
      for (int i = 0; i < 4; ++i) {
        const int rch = bM + wm + mf * 16 + (g << 2) + i;
        const float bb = bias[rch];
        const int h = rch >> 6, d = rch & 63;
#pragma unroll
        for (int nf = 0; nf < 2; ++nf) {
          const int t = bN + wn + nf * 16 + l15;
          const int b = t & 1, s = t >> 1;
          Vo[((((b << 4) + h) << 6) + d) * SEQ + s] = f2bf(acc[mf][nf][i] + bb);
        }
      }
  }
}

// ---------------- O projection: fp32 out, double-buffered ----------------
__global__ __launch_bounds__(512) void gemm_oproj(const unsigned short* __restrict__ A,
                                                  const unsigned short* __restrict__ B,
                                                  const float* __restrict__ bias,
                                                  float* __restrict__ O) {
  __shared__ unsigned short sA[2][128 * 32];
  __shared__ unsigned short sB[2][128 * 32];
  const int tid  = threadIdx.x;
  const int lane = tid & 63;
  const int wave = tid >> 6;
  const int wm   = (wave >> 2) << 6;
  const int wn   = (wave & 3) << 5;
  const int l15  = lane & 15;
  const int g    = lane >> 4;
  const int bM   = blockIdx.y << 7;
  const int bN   = blockIdx.x << 7;

  f32x4 acc[4][2];
#pragma unroll
  for (int a_ = 0; a_ < 4; ++a_)
#pragma unroll
    for (int b_ = 0; b_ < 2; ++b_)
      acc[a_][b_] = f32x4{0.f, 0.f, 0.f, 0.f};

  const int r = tid >> 2, cc = tid & 3;
  auto stage = [&](int c, int kt) {
    const int k0 = kt << 5;
    gload_lds16(A + (size_t)(bM + r) * MD + k0 + cc * 8, (char*)sA[c] + tid * 16);
    gload_lds16(B + (size_t)(bN + r) * MD + k0 + cc * 8, (char*)sB[c] + tid * 16);
  };

  stage(0, 0);
  __syncthreads();
  int cur = 0;
  const int nk = MD >> 5;
  for (int kt = 0; kt < nk; ++kt) {
    if (kt + 1 < nk) stage(cur ^ 1, kt + 1);
    bf16x8 af[4], bfr[2];
#pragma unroll
    for (int f = 0; f < 4; ++f)
      af[f] = *(const bf16x8*)&sA[cur][(wm + f * 16 + l15) * 32 + g * 8];
#pragma unroll
    for (int f = 0; f < 2; ++f)
      bfr[f] = *(const bf16x8*)&sB[cur][(wn + f * 16 + l15) * 32 + g * 8];
#pragma unroll
    for (int mf = 0; mf < 4; ++mf)
#pragma unroll
      for (int nf = 0; nf < 2; ++nf)
        acc[mf][nf] = __builtin_amdgcn_mfma_f32_16x16x32_bf16(af[mf], bfr[nf], acc[mf][nf], 0, 0, 0);
    __syncthreads();
    cur ^= 1;
  }

#pragma unroll
  for (int nf = 0; nf < 2; ++nf) {
    const int cch = bN + wn + nf * 16 + l15;
    const float bb = bias[cch];
#pragma unroll
    for (int mf = 0; mf < 4; ++mf)
#pragma unroll
      for (int i = 0; i < 4; ++i) {
        const int t = bM + wm + mf * 16 + (g << 2) + i;
        O[(size_t)t * MD + cch] = acc[mf][nf][i] + bb;
      }
  }
}

// --------------- flash attention, swapped-operand 32x32 -----------------
// grid (SEQ/128, 32bh) = 512 blocks, 4 waves; wave owns 32 q-rows (q=lane&31,
// lane pair l/l^32 splits the k-dim). QK^T = mfma(K,Q) -> S[k,q]; softmax
// fully in-register (1 shfl per tile); P->bf16 via cvt_pk + permlane32_swap;
// PV = mfma(V^T,P) -> O[d,q] keeps q=lane&31 so rescale is lane-uniform.
// Q [B,H,S,D] pre-scaled by log2e/8; K [B,H,S,D]; V^T [B,H,D,S].
__global__ __launch_bounds__(256) void attn_fwd(const unsigned short* __restrict__ Qg,
                                                const unsigned short* __restrict__ Kg,
                                                const unsigned short* __restrict__ Vg,
                                                unsigned short* __restrict__ Xout) {
  __shared__ unsigned short sK[2][64 * 64];  // [k][d], XOR-swizzled
  __shared__ unsigned short sV[2][64 * 64];  // [d][k], XOR-swizzled

  const int tid  = threadIdx.x;
  const int lane = tid & 63;
  const int wave = tid >> 6;
  const int l31  = lane & 31;
  const int half = lane >> 5;
  const int bh   = blockIdx.y;
  const int q0w  = (blockIdx.x << 7) + (wave << 5);   // this wave's q base

  const unsigned short* Qb = Qg + (size_t)bh * (SEQ * HD);
  const unsigned short* Kb = Kg + (size_t)bh * (SEQ * HD);
  const unsigned short* Vb = Vg + (size_t)bh * (HD * SEQ);

  // Q fragments as MFMA B-operand: lane holds Q[q=l31][c*16 + half*8 ..+8]
  bf16x8 qf[4];
#pragma unroll
  for (int c = 0; c < 4; ++c)
    qf[c] = *(const bf16x8*)&Qb[(size_t)(q0w + l31) * HD + c * 16 + half * 8];

  f32x16 acc_o[2];
#pragma unroll
  for (int dt = 0; dt < 2; ++dt)
#pragma unroll
    for (int e = 0; e < 16; ++e) acc_o[dt][e] = 0.f;
  float mrow = -1e30f, lrow = 0.f;

  // stage K [64 k][64 d] and V^T [64 d][64 k]: linear LDS dest,
  // inverse-swizzled global source (swizzle: byte ^= (row&7)<<4)
  auto stage = [&](int c, int kt) {
    const int k0 = kt << 6;
#pragma unroll
    for (int j = 0; j < 2; ++j) {
      const int p = (tid + (j << 8)) << 4;
      const int row = p >> 7;
      const int lcol = (p ^ ((row & 7) << 4)) & 127;
      gload_lds16((const char*)Kb + (size_t)(k0 + row) * (HD * 2) + lcol, (char*)sK[c] + p);
      gload_lds16((const char*)Vb + (size_t)row * (SEQ * 2) + (k0 << 1) + lcol, (char*)sV[c] + p);
    }
  };

  stage(0, 0);
  __syncthreads();
  int cur = 0;

  for (int kt = 0; kt < SEQ / 64; ++kt) {
    if (kt + 1 < SEQ / 64) stage(cur ^ 1, kt + 1);   // prefetch next tile

    // S = K·Q^T: accs[ks] is a 32k x 32q C-tile; lane: q=l31, 16 k's/reg set
    f32x16 accs[2];
#pragma unroll
    for (int ks = 0; ks < 2; ++ks) {
#pragma unroll
      for (int e = 0; e < 16; ++e) accs[ks][e] = 0.f;
      const int krow = ks * 32 + l31;
      const int swz  = (krow & 7) << 4;
#pragma unroll
      for (int c = 0; c < 4; ++c) {
        const int off = (krow << 7) + ((c * 32 + half * 16) ^ swz);
        bf16x8 kf = *(const bf16x8*)((const char*)sK[cur] + off);
        accs[ks] = __builtin_amdgcn_mfma_f32_32x32x16_bf16(kf, qf[c], accs[ks], 0, 0, 0);
      }
    }

    // online softmax, base-2; lane pair l/l^32 shares q, splits k
    float mx = accs[0][0];
#pragma unroll
    for (int ks = 0; ks < 2; ++ks)
#pragma unroll
      for (int e = 0; e < 16; ++e) mx = fmaxf(mx, accs[ks][e]);
    mx = fmaxf(mx, __shfl_xor(mx, 32));
    const float mnew = fmaxf(mrow, mx);
    const float resc = __builtin_amdgcn_exp2f(mrow - mnew);
    mrow = mnew;
    float rsum = 0.f;
#pragma unroll
    for (int ks = 0; ks < 2; ++ks)
#pragma unroll
      for (int e = 0; e < 16; ++e) {
        const float pv = __builtin_amdgcn_exp2f(accs[ks][e] - mnew);
        accs[ks][e] = pv;
        rsum += pv;
      }
    lrow = lrow * resc + rsum;          // per-lane partial (half the k's)
#pragma unroll
    for (int dt = 0; dt < 2; ++dt)
#pragma unroll
      for (int e = 0; e < 16; ++e) acc_o[dt][e] *= resc;

    // P -> bf16 MFMA operand frags, in-register (T12):
    // pa[ks*2+hc] covers k = ks*32 + hc*16 .. +15 for this lane's q
    bf16x8 pa[4];
#pragma unroll
    for (int ks = 0; ks < 2; ++ks)
#pragma unroll
      for (int hc = 0; hc < 2; ++hc) {
        const int b = hc * 8;
        unsigned X  = cvtpk(accs[ks][b + 0], accs[ks][b + 1]);
        unsigned X2 = cvtpk(accs[ks][b + 2], accs[ks][b + 3]);
        unsigned Y  = cvtpk(accs[ks][b + 4], accs[ks][b + 5]);
        unsigned Y2 = cvtpk(accs[ks][b + 6], accs[ks][b + 7]);
        plswap(X, Y);                   // X=(k0k1|k8k9)  Y=(k4k5|k12k13)
        plswap(X2, Y2);                 // X2=(k2k3|k10k11) Y2=(k6k7|k14k15)
        union { unsigned u[4]; bf16x8 v; } w;
        w.u[0] = X; w.u[1] = X2; w.u[2] = Y; w.u[3] = Y2;
        pa[ks * 2 + hc] = w.v;
      }

    // O^T += V^T · P^T : acc_o[dt] = mfma(A=V^T rows d, B=P rows q)
#pragma unroll
    for (int dt = 0; dt < 2; ++dt) {
      const int drow = dt * 32 + l31;
      const int swz  = (drow & 7) << 4;
#pragma unroll
      for (int kc = 0; kc < 4; ++kc) {
        const int off = (drow << 7) + ((kc * 32 + half * 16) ^ swz);
        bf16x8 vf = *(const bf16x8*)((const char*)sV[cur] + off);
        acc_o[dt] = __builtin_amdgcn_mfma_f32_32x32x16_bf16(vf, pa[kc], acc_o[dt], 0, 0, 0);
      }
    }

    __syncthreads();
    cur ^= 1;
  }

  // epilogue: total l over the lane pair, then write O[q, d]/l
  float lt = lrow + __shfl_xor(lrow, 32);
  const float inv = 1.f / lt;
  const int b = bh >> 4, h = bh & 15;
  const int s = q0w + l31;
  const int t = s * NBATCH + b;
  unsigned short* Ot = Xout + (size_t)t * MD + (h << 6);
#pragma unroll
  for (int dt = 0; dt < 2; ++dt)
#pragma unroll
    for (int r4 = 0; r4 < 4; ++r4) {
      const int d0 = dt * 32 + r4 * 8 + half * 4;       // 4 consecutive d
      const int e = r4 * 4;
      uint2 w;
      w.x = cvtpk(acc_o[dt][e + 0] * inv, acc_o[dt][e + 1] * inv);
      w.y = cvtpk(acc_o[dt][e + 2] * inv, acc_o[dt][e + 3] * inv);
      *(uint2*)(Ot + d0) = w;
    }
}

extern "C" void kernel_launch(void* const* d_in, const int* in_sizes, int n_in,
                              void* d_out, int out_size, void* d_ws, size_t ws_size,
                              hipStream_t stream) {
  const float* query = (const float*)d_in[0];
  const float* key   = (const float*)d_in[1];
  const float* value = (const float*)d_in[2];
  // d_in[3] = mask: dead code in reference
  const float* Wq = (const float*)d_in[4];
  const float* bq = (const float*)d_in[5];
  const float* Wk = (const float*)d_in[6];
  const float* bk = (const float*)d_in[7];
  const float* Wv = (const float*)d_in[8];
  const float* bv = (const float*)d_in[9];
  const float* Wo = (const float*)d_in[10];
  const float* bo = (const float*)d_in[11];

  char* ws = (char*)d_ws;
  const size_t MB = 1024 * 1024;
  unsigned short* Xq  = (unsigned short*)(ws + 0 * MB);   // [TOK,MD] bf16
  unsigned short* Xk  = (unsigned short*)(ws + 8 * MB);
  unsigned short* Xv  = (unsigned short*)(ws + 16 * MB);
  unsigned short* Wqb = (unsigned short*)(ws + 24 * MB);
  unsigned short* Wkb = (unsigned short*)(ws + 26 * MB);
  unsigned short* Wvb = (unsigned short*)(ws + 28 * MB);
  unsigned short* Wob = (unsigned short*)(ws + 30 * MB);
  unsigned short* Qb  = (unsigned short*)(ws + 32 * MB);  // [B,H,S,D]
  unsigned short* Kb  = (unsigned short*)(ws + 40 * MB);  // [B,H,S,D]
  unsigned short* Vb  = (unsigned short*)(ws + 48 * MB);  // [B,H,D,S]
  unsigned short* Xa  = Xq;  // alias: Xq dead after Q projection

  cvt_all<<<(3 * XN8 + 4 * WN8) / 256, 256, 0, stream>>>(
      query, key, value, Wq, Wk, Wv, Wo, Xq, Xk, Xv, Wqb, Wkb, Wvb, Wob);

  const float kQScale = 0.125f * 1.44269504088896340736f;  // (1/sqrt(64))*log2(e)
  dim3 gQKV(MD / 128, TOK / 128, 3);   // (8, 32, 3) = 768 blocks
  gemm_qkv<<<gQKV, 512, 0, stream>>>(Xq, Xk, Xv, Wqb, Wkb, Wvb,
                                     bq, bk, bv, Qb, Kb, Vb, kQScale);

  dim3 gA(SEQ / 128, NBATCH * NHEAD);  // (16, 32) = 512 blocks
  attn_fwd<<<gA, 256, 0, stream>>>(Qb, Kb, Vb, Xa);

  dim3 gO(MD / 128, TOK / 128);        // (8, 32)
  gemm_oproj<<<gO, 512, 0, stream>>>(Xa, Wob, bo, (float*)d_out);
  (void)in_sizes; (void)n_in; (void)out_size; (void)ws_size;
}